// Round 3
// baseline (5866.138 us; speedup 1.0000x reference)
//
#include <hip/hip_runtime.h>
#include <float.h>

#define NROWS 16384
#define NE    8192
#define DIM   512
#define RPB   32          // z rows per block
#define NSP   16          // n-range splits (threads per row)
#define NSTEP (NE / NSP)  // 512 n-steps
#define LDE   (DIM + 4)   // padded LDS row stride (floats), keeps 16B align

// Emulate numpy-float32 reference bit-exactly:
//   d = fl32( A  -  fl32(2*G) )      [ ||e||^2 vanishes: < half-ulp(A) always ]
//   G = numpy einsum fp32, baseline-SSE npyv order:
//       4 lanes, chunks of 16, product order k=3,2,1,0 within chunk,
//       mul and add separately rounded (no FMA), hsum (L0+L1)+(L2+L3)
//   argmin with first-index tie-break.
#define STEP(zk, ek)                                  \
  L0 = __fadd_rn(L0, __fmul_rn((zk).x, (ek).x));      \
  L1 = __fadd_rn(L1, __fmul_rn((zk).y, (ek).y));      \
  L2 = __fadd_rn(L2, __fmul_rn((zk).z, (ek).z));      \
  L3 = __fadd_rn(L3, __fmul_rn((zk).w, (ek).w));

__global__ __launch_bounds__(512) void k_vq_np32(
    const float* __restrict__ z, const float* __restrict__ cb,
    float* __restrict__ out) {
  __shared__ __align__(16) float zs[RPB][LDE];   // 66 KB
  __shared__ __align__(16) float es[NSP][LDE];   // 33 KB
  __shared__ float rd[RPB][NSP];
  __shared__ int   rn[RPB][NSP];
  __shared__ int   fidx[RPB];

  const int t  = threadIdx.x;
  const int mi = t & 31, sp = t >> 5;
  const int mBase = blockIdx.x * RPB;

  // stage z rows: 32 x 128 float4
  #pragma unroll
  for (int i = 0; i < 8; ++i) {
    int li = t + i * 512;
    int r = li >> 7, q = li & 127;
    *(float4*)&zs[r][q * 4] =
        *(const float4*)(z + (size_t)(mBase + r) * DIM + q * 4);
  }
  __syncthreads();

  // A = fl32(||z||^2): f64 accumulate, round once. Row-constant ulp-offsets vs
  // numpy's pairwise fp32 sum shift d by exact grid multiples -> argmin invariant.
  double a64 = 0.0;
  for (int k = 0; k < DIM; ++k) { double v = (double)zs[mi][k]; a64 += v * v; }
  const float A32 = (float)a64;

  float bd = FLT_MAX; int bn = 0;

  for (int s = 0; s < NSTEP; ++s) {
    __syncthreads();
    // stage e rows { r*NSTEP + s : r in [0,16) }: 16 x 128 float4
    #pragma unroll
    for (int i = 0; i < 4; ++i) {
      int li = t + i * 512;
      int r = li >> 7, q = li & 127;
      *(float4*)&es[r][q * 4] =
          *(const float4*)(cb + (size_t)(r * NSTEP + s) * DIM + q * 4);
    }
    __syncthreads();

    float L0 = 0.f, L1 = 0.f, L2 = 0.f, L3 = 0.f;
    #pragma unroll
    for (int c = 0; c < 32; ++c) {
      float4 z0 = *(const float4*)&zs[mi][c * 16];
      float4 z1 = *(const float4*)&zs[mi][c * 16 + 4];
      float4 z2 = *(const float4*)&zs[mi][c * 16 + 8];
      float4 z3 = *(const float4*)&zs[mi][c * 16 + 12];
      float4 e0 = *(const float4*)&es[sp][c * 16];
      float4 e1 = *(const float4*)&es[sp][c * 16 + 4];
      float4 e2 = *(const float4*)&es[sp][c * 16 + 8];
      float4 e3 = *(const float4*)&es[sp][c * 16 + 12];
      STEP(z3, e3)   // npyv chain: ab3 first
      STEP(z2, e2)
      STEP(z1, e1)
      STEP(z0, e0)
    }
    float G = __fadd_rn(__fadd_rn(L0, L1), __fadd_rn(L2, L3));
    float d = __fsub_rn(A32, __fmul_rn(2.0f, G));
    // n ascending in s -> strict < keeps first index within this thread
    if (d < bd) { bd = d; bn = sp * NSTEP + s; }
  }

  rd[mi][sp] = bd; rn[mi][sp] = bn;
  __syncthreads();

  if (t < RPB) {
    // sp ascending = n ascending ranges: strict < + equal-keep = global first index
    float fbd = FLT_MAX; int fbn = 0;
    for (int c = 0; c < NSP; ++c) {
      float dv = rd[t][c]; int nv = rn[t][c];
      if (dv < fbd || (dv == fbd && nv < fbn)) { fbd = dv; fbn = nv; }
    }
    fidx[t] = fbn;
    out[(size_t)NROWS * DIM + (mBase + t)] = (float)fbn;
  }
  __syncthreads();

  // gather z_q: 32 rows x 128 float4 = 4096 float4, 8 per thread
  #pragma unroll
  for (int i = 0; i < 8; ++i) {
    int li = t + i * 512;
    int r = li >> 7, q = li & 127;
    int idx = fidx[r];
    *(float4*)(out + (size_t)(mBase + r) * DIM + q * 4) =
        *(const float4*)(cb + (size_t)idx * DIM + q * 4);
  }
}

extern "C" void kernel_launch(void* const* d_in, const int* in_sizes, int n_in,
                              void* d_out, int out_size, void* d_ws, size_t ws_size,
                              hipStream_t stream) {
    const float* z  = (const float*)d_in[0];
    const float* cb = (const float*)d_in[1];
    float* out = (float*)d_out;
    hipLaunchKernelGGL(k_vq_np32, dim3(NROWS / RPB), dim3(512), 0, stream, z, cb, out);
}

// Round 4
// 4768.459 us; speedup vs baseline: 1.2302x; 1.2302x over previous
//
#include <hip/hip_runtime.h>
#include <float.h>
#include <limits.h>

#define NROWS 16384
#define NE    8192
#define DIM   512

// ---- fast pass geometry ----
#define TMF 128
#define TNF 128
#define NSPLITF 4
#define NRANGE (NE / NSPLITF)   // 2048
#define KBF 32
#define LDF 130                 // k-major LDS row stride (floats): 2-way banks max

// ---- refine geometry ----
#define RROWS 16
#define LDR (DIM + 4)           // 516: float4-aligned, 2-way banks

// ---- workspace layout (bytes); total 917508 < proven-safe ~1.0 MB ----
#define WS_PM1  0               // float[NROWS*4]
#define WS_PM2  262144          // float[NROWS*4]
#define WS_PI1  524288          // int[NROWS*4]
#define WS_FIDX 786432          // int[NROWS]
#define WS_LIST 851968          // int[NROWS]
#define WS_CNT  917504          // int

// exact npyv (baseline-SSE) chain step: 4 lanes, mul and add separately rounded
#define STEP(zk, ek)                                  \
  L0 = __fadd_rn(L0, __fmul_rn((zk).x, (ek).x));      \
  L1 = __fadd_rn(L1, __fmul_rn((zk).y, (ek).y));      \
  L2 = __fadd_rn(L2, __fmul_rn((zk).z, (ek).z));      \
  L3 = __fadd_rn(L3, __fmul_rn((zk).w, (ek).w));

// ---------------- K1: fast fp32-FMA GEMM-max over G = z.e ----------------
// grid (NROWS/TMF, NSPLITF), block 256 (tx16 x ty16), thread tile 8m x 8n
__global__ __launch_bounds__(256) void k_fast(
    const float* __restrict__ z, const float* __restrict__ cb,
    float* __restrict__ pm1, float* __restrict__ pm2, int* __restrict__ pi1,
    int* __restrict__ counter) {
  __shared__ __align__(16) float zs[KBF][LDF];   // k-major: [k][m]
  __shared__ __align__(16) float es[KBF][LDF];   // k-major: [k][n]

  const int t  = threadIdx.x;
  const int tx = t & 15, ty = t >> 4;
  const int mBase  = blockIdx.x * TMF;
  const int nBase0 = blockIdx.y * NRANGE;
  if (blockIdx.x == 0 && blockIdx.y == 0 && t == 0) *counter = 0;

  float m1[8], m2[8]; int i1[8];
  #pragma unroll
  for (int r = 0; r < 8; ++r) { m1[r] = -FLT_MAX; m2[r] = -FLT_MAX; i1[r] = 0; }

  for (int nt = 0; nt < NRANGE / TNF; ++nt) {     // 16 n-tiles
    const int nBase = nBase0 + nt * TNF;
    float acc[8][8];
    #pragma unroll
    for (int r = 0; r < 8; ++r)
      #pragma unroll
      for (int j = 0; j < 8; ++j) acc[r][j] = 0.0f;

    for (int kc = 0; kc < DIM; kc += KBF) {       // 16 k-chunks
      __syncthreads();                            // prev-iter LDS reads done
      // stage z chunk transposed: 128 rows x 32 k (2-way bank on stores)
      #pragma unroll
      for (int i = 0; i < 4; ++i) {
        int li = t + i * 256, r = li >> 3, q = li & 7;
        float4 v = *(const float4*)(z + (size_t)(mBase + r) * DIM + kc + q * 4);
        zs[q*4+0][r] = v.x; zs[q*4+1][r] = v.y; zs[q*4+2][r] = v.z; zs[q*4+3][r] = v.w;
      }
      // stage e chunk transposed
      #pragma unroll
      for (int i = 0; i < 4; ++i) {
        int li = t + i * 256, r = li >> 3, q = li & 7;
        float4 v = *(const float4*)(cb + (size_t)(nBase + r) * DIM + kc + q * 4);
        es[q*4+0][r] = v.x; es[q*4+1][r] = v.y; es[q*4+2][r] = v.z; es[q*4+3][r] = v.w;
      }
      __syncthreads();
      #pragma unroll
      for (int kk = 0; kk < KBF; ++kk) {
        float2 zf[4], ef[4];
        #pragma unroll
        for (int i = 0; i < 4; ++i) zf[i] = *(const float2*)&zs[kk][ty * 8 + 2 * i];
        #pragma unroll
        for (int j = 0; j < 4; ++j) ef[j] = *(const float2*)&es[kk][2 * tx + 32 * j];
        #pragma unroll
        for (int i = 0; i < 4; ++i)
          #pragma unroll
          for (int j = 0; j < 4; ++j) {
            acc[2*i  ][2*j  ] = fmaf(zf[i].x, ef[j].x, acc[2*i  ][2*j  ]);
            acc[2*i  ][2*j+1] = fmaf(zf[i].x, ef[j].y, acc[2*i  ][2*j+1]);
            acc[2*i+1][2*j  ] = fmaf(zf[i].y, ef[j].x, acc[2*i+1][2*j  ]);
            acc[2*i+1][2*j+1] = fmaf(zf[i].y, ef[j].y, acc[2*i+1][2*j+1]);
          }
      }
    }
    // fold into per-thread top-2 (n ascending within thread -> first-index kept)
    #pragma unroll
    for (int r = 0; r < 8; ++r)
      #pragma unroll
      for (int j = 0; j < 4; ++j)
        #pragma unroll
        for (int c = 0; c < 2; ++c) {
          float g = acc[r][2*j+c];
          int   n = nBase + 2 * tx + 32 * j + c;
          if (g > m1[r]) { m2[r] = m1[r]; m1[r] = g; i1[r] = n; }
          else if (g > m2[r]) m2[r] = g;
        }
  }

  __syncthreads();
  // cross-tx per-row reduce; reuse tile LDS as scratch
  float* rm1 = &zs[0][0];           // 2048 floats  (zs holds 4160)
  float* rm2 = &zs[0][0] + 2048;    // 2048 floats
  int*   ri1 = (int*)&es[0][0];     // 2048 ints
  #pragma unroll
  for (int r = 0; r < 8; ++r) {
    int row = ty * 8 + r;
    rm1[row * 16 + tx] = m1[r]; rm2[row * 16 + tx] = m2[r]; ri1[row * 16 + tx] = i1[r];
  }
  __syncthreads();
  if (t < TMF) {
    float M1 = -FLT_MAX, M2 = -FLT_MAX; int I1 = INT_MAX;
    for (int c = 0; c < 16; ++c) {
      float a1 = rm1[t * 16 + c], a2 = rm2[t * 16 + c]; int ai = ri1[t * 16 + c];
      if (a1 > M1 || (a1 == M1 && ai < I1)) { M2 = fmaxf(M1, a2); M1 = a1; I1 = ai; }
      else M2 = fmaxf(M2, a1);
    }
    size_t gm = (size_t)(mBase + t);
    pm1[gm * NSPLITF + blockIdx.y] = M1;
    pm2[gm * NSPLITF + blockIdx.y] = M2;
    pi1[gm * NSPLITF + blockIdx.y] = I1;
  }
}

// ---------------- K2: merge splits, compute A, flag near-ties ----------------
__global__ void k_merge(const float* __restrict__ z,
                        const float* __restrict__ pm1, const float* __restrict__ pm2,
                        const int* __restrict__ pi1,
                        int* __restrict__ fidx, int* __restrict__ list,
                        int* __restrict__ counter) {
  int m = blockIdx.x * 256 + threadIdx.x;
  float M1 = -FLT_MAX, M2 = -FLT_MAX; int I1 = INT_MAX;
  #pragma unroll
  for (int s = 0; s < NSPLITF; ++s) {
    float a1 = pm1[(size_t)m * NSPLITF + s], a2 = pm2[(size_t)m * NSPLITF + s];
    int   ai = pi1[(size_t)m * NSPLITF + s];
    if (a1 > M1 || (a1 == M1 && ai < I1)) { M2 = fmaxf(M1, a2); M1 = a1; I1 = ai; }
    else M2 = fmaxf(M2, a1);
  }
  // A = fl32(f64 sum z^2) — validated semantics (round 2)
  double A = 0.0;
  const float4* zr = (const float4*)(z + (size_t)m * DIM);
  for (int q = 0; q < DIM / 4; ++q) {
    float4 v = zr[q];
    A += (double)v.x * v.x + (double)v.y * v.y + (double)v.z * v.z + (double)v.w * v.w;
  }
  float A32 = (float)A;
  // tau in G units: d-tie needs 2*Ggap < ~2 ulp(d); margin for chain errors
  float u   = (A32 > 511.8f) ? 6.1035156e-5f : 3.0517578e-5f;
  float tau = 1.25f * u + 2.0e-6f;
  fidx[m] = I1;
  if (M1 - M2 < tau) { int p = atomicAdd(counter, 1); list[p] = m; }
}

// ---------------- K3: exact npyv rescan of flagged rows (16 rows/block) ----------------
__global__ __launch_bounds__(256) void k_refine(
    const float* __restrict__ z, const float* __restrict__ cb,
    const int* __restrict__ list, const int* __restrict__ counter,
    int* __restrict__ fidx) {
  __shared__ __align__(16) float zsr[RROWS][LDR];
  __shared__ __align__(16) float est[RROWS][LDR];
  __shared__ double apart[RROWS][16];
  __shared__ float  Arow[RROWS];
  __shared__ int    mrow[RROWS];
  __shared__ float  rdm[RROWS][16];
  __shared__ int    rnm[RROWS][16];

  const int cnt = *counter;
  const int t = threadIdx.x;
  const int groupBase = blockIdx.x * RROWS;
  if (groupBase >= cnt) return;                       // uniform exit

  if (t < RROWS)
    mrow[t] = (groupBase + t < cnt) ? list[groupBase + t] : list[cnt - 1];
  __syncthreads();

  #pragma unroll
  for (int i = 0; i < 8; ++i) {                       // stage 16 z rows
    int li = t + i * 256, r = li >> 7, q = li & 127;
    *(float4*)&zsr[r][q * 4] = *(const float4*)(z + (size_t)mrow[r] * DIM + q * 4);
  }
  __syncthreads();
  {                                                   // A per row (f64)
    int r = t >> 4, seg = t & 15;
    double s = 0.0;
    for (int k = seg * 32; k < seg * 32 + 32; ++k) { double v = zsr[r][k]; s += v * v; }
    apart[r][seg] = s;
  }
  __syncthreads();
  if (t < RROWS) { double s = 0.0; for (int c = 0; c < 16; ++c) s += apart[t][c]; Arow[t] = (float)s; }

  const int r = t >> 4, c = t & 15;
  float bd = FLT_MAX; int bn = 0;
  for (int tile = 0; tile < NE / RROWS; ++tile) {     // 512 e-tiles of 16 rows
    __syncthreads();
    #pragma unroll
    for (int i = 0; i < 8; ++i) {
      int li = t + i * 256, rr = li >> 7, q = li & 127;
      *(float4*)&est[rr][q * 4] =
          *(const float4*)(cb + (size_t)(tile * RROWS + rr) * DIM + q * 4);
    }
    __syncthreads();
    float L0 = 0.f, L1 = 0.f, L2 = 0.f, L3 = 0.f;
    #pragma unroll
    for (int ch = 0; ch < 32; ++ch) {
      float4 z0 = *(const float4*)&zsr[r][ch * 16];
      float4 z1 = *(const float4*)&zsr[r][ch * 16 + 4];
      float4 z2 = *(const float4*)&zsr[r][ch * 16 + 8];
      float4 z3 = *(const float4*)&zsr[r][ch * 16 + 12];
      float4 e0 = *(const float4*)&est[c][ch * 16];
      float4 e1 = *(const float4*)&est[c][ch * 16 + 4];
      float4 e2 = *(const float4*)&est[c][ch * 16 + 8];
      float4 e3 = *(const float4*)&est[c][ch * 16 + 12];
      STEP(z3, e3) STEP(z2, e2) STEP(z1, e1) STEP(z0, e0)
    }
    float G = __fadd_rn(__fadd_rn(L0, L1), __fadd_rn(L2, L3));
    float d = __fsub_rn(Arow[r], __fmul_rn(2.0f, G));
    int   n = tile * RROWS + c;
    if (d < bd) { bd = d; bn = n; }                  // n ascending per thread
  }
  __syncthreads();
  rdm[r][c] = bd; rnm[r][c] = bn;
  __syncthreads();
  if (t < RROWS) {
    float fb = FLT_MAX; int fn = INT_MAX;
    for (int cc = 0; cc < 16; ++cc) {
      float dv = rdm[t][cc]; int nv = rnm[t][cc];
      if (dv < fb || (dv == fb && nv < fn)) { fb = dv; fn = nv; }
    }
    if (groupBase + t < cnt) fidx[mrow[t]] = fn;
  }
}

// ---------------- K4: gather z_q + index floats ----------------
__global__ void k_gather(const float* __restrict__ cb, const int* __restrict__ fidx,
                         float* __restrict__ out) {
  __shared__ int idxs[32];
  const int t = threadIdx.x;
  const int mBase = blockIdx.x * 32;
  if (t < 32) {
    int id = fidx[mBase + t];
    idxs[t] = id;
    out[(size_t)NROWS * DIM + mBase + t] = (float)id;
  }
  __syncthreads();
  #pragma unroll
  for (int i = 0; i < 16; ++i) {
    int li = t + i * 256, r = li >> 7, q = li & 127;
    *(float4*)(out + (size_t)(mBase + r) * DIM + q * 4) =
        *(const float4*)(cb + (size_t)idxs[r] * DIM + q * 4);
  }
}

extern "C" void kernel_launch(void* const* d_in, const int* in_sizes, int n_in,
                              void* d_out, int out_size, void* d_ws, size_t ws_size,
                              hipStream_t stream) {
  const float* z  = (const float*)d_in[0];
  const float* cb = (const float*)d_in[1];
  float* out = (float*)d_out;
  char* ws = (char*)d_ws;
  float* pm1 = (float*)(ws + WS_PM1);
  float* pm2 = (float*)(ws + WS_PM2);
  int*   pi1 = (int*)(ws + WS_PI1);
  int*   fidx = (int*)(ws + WS_FIDX);
  int*   list = (int*)(ws + WS_LIST);
  int*   cnt  = (int*)(ws + WS_CNT);

  hipLaunchKernelGGL(k_fast,   dim3(NROWS / TMF, NSPLITF), dim3(256), 0, stream,
                     z, cb, pm1, pm2, pi1, cnt);
  hipLaunchKernelGGL(k_merge,  dim3(NROWS / 256), dim3(256), 0, stream,
                     z, pm1, pm2, pi1, fidx, list, cnt);
  hipLaunchKernelGGL(k_refine, dim3(NROWS / RROWS), dim3(256), 0, stream,
                     z, cb, list, cnt, fidx);
  hipLaunchKernelGGL(k_gather, dim3(NROWS / 32), dim3(256), 0, stream,
                     cb, fidx, out);
}

// Round 5
// 2703.078 us; speedup vs baseline: 2.1702x; 1.7641x over previous
//
#include <hip/hip_runtime.h>
#include <float.h>
#include <limits.h>

#define NROWS 16384
#define NE    8192
#define DIM   512

// ---- fast pass geometry ----
#define TMF 128
#define TNF 128
#define NSPLITF 4
#define NRANGE (NE / NSPLITF)   // 2048
#define KBF 32
#define LDF 130                 // k-major LDS row stride (floats)

// ---- workspace layout (bytes) ----
#define WS_PM1  0               // float[NROWS*4]  (reused as refine partial d)
#define WS_PM2  262144          // float[NROWS*4]
#define WS_PI1  524288          // int[NROWS*4]    (reused as refine partial n)
#define WS_FIDX 786432          // int[NROWS]
#define WS_LIST 851968          // int[NROWS]
#define WS_CNT  917504          // int

// ---------------- K1: fast fp32-FMA GEMM-max over G = z.e (unchanged) ----------------
__global__ __launch_bounds__(256) void k_fast(
    const float* __restrict__ z, const float* __restrict__ cb,
    float* __restrict__ pm1, float* __restrict__ pm2, int* __restrict__ pi1,
    int* __restrict__ counter) {
  __shared__ __align__(16) float zs[KBF][LDF];
  __shared__ __align__(16) float es[KBF][LDF];

  const int t  = threadIdx.x;
  const int tx = t & 15, ty = t >> 4;
  const int mBase  = blockIdx.x * TMF;
  const int nBase0 = blockIdx.y * NRANGE;
  if (blockIdx.x == 0 && blockIdx.y == 0 && t == 0) *counter = 0;

  float m1[8], m2[8]; int i1[8];
  #pragma unroll
  for (int r = 0; r < 8; ++r) { m1[r] = -FLT_MAX; m2[r] = -FLT_MAX; i1[r] = 0; }

  for (int nt = 0; nt < NRANGE / TNF; ++nt) {
    const int nBase = nBase0 + nt * TNF;
    float acc[8][8];
    #pragma unroll
    for (int r = 0; r < 8; ++r)
      #pragma unroll
      for (int j = 0; j < 8; ++j) acc[r][j] = 0.0f;

    for (int kc = 0; kc < DIM; kc += KBF) {
      __syncthreads();
      #pragma unroll
      for (int i = 0; i < 4; ++i) {
        int li = t + i * 256, r = li >> 3, q = li & 7;
        float4 v = *(const float4*)(z + (size_t)(mBase + r) * DIM + kc + q * 4);
        zs[q*4+0][r] = v.x; zs[q*4+1][r] = v.y; zs[q*4+2][r] = v.z; zs[q*4+3][r] = v.w;
      }
      #pragma unroll
      for (int i = 0; i < 4; ++i) {
        int li = t + i * 256, r = li >> 3, q = li & 7;
        float4 v = *(const float4*)(cb + (size_t)(nBase + r) * DIM + kc + q * 4);
        es[q*4+0][r] = v.x; es[q*4+1][r] = v.y; es[q*4+2][r] = v.z; es[q*4+3][r] = v.w;
      }
      __syncthreads();
      #pragma unroll
      for (int kk = 0; kk < KBF; ++kk) {
        float2 zf[4], ef[4];
        #pragma unroll
        for (int i = 0; i < 4; ++i) zf[i] = *(const float2*)&zs[kk][ty * 8 + 2 * i];
        #pragma unroll
        for (int j = 0; j < 4; ++j) ef[j] = *(const float2*)&es[kk][2 * tx + 32 * j];
        #pragma unroll
        for (int i = 0; i < 4; ++i)
          #pragma unroll
          for (int j = 0; j < 4; ++j) {
            acc[2*i  ][2*j  ] = fmaf(zf[i].x, ef[j].x, acc[2*i  ][2*j  ]);
            acc[2*i  ][2*j+1] = fmaf(zf[i].x, ef[j].y, acc[2*i  ][2*j+1]);
            acc[2*i+1][2*j  ] = fmaf(zf[i].y, ef[j].x, acc[2*i+1][2*j  ]);
            acc[2*i+1][2*j+1] = fmaf(zf[i].y, ef[j].y, acc[2*i+1][2*j+1]);
          }
      }
    }
    #pragma unroll
    for (int r = 0; r < 8; ++r)
      #pragma unroll
      for (int j = 0; j < 4; ++j)
        #pragma unroll
        for (int c = 0; c < 2; ++c) {
          float g = acc[r][2*j+c];
          int   n = nBase + 2 * tx + 32 * j + c;
          if (g > m1[r]) { m2[r] = m1[r]; m1[r] = g; i1[r] = n; }
          else if (g > m2[r]) m2[r] = g;
        }
  }

  __syncthreads();
  float* rm1 = &zs[0][0];
  float* rm2 = &zs[0][0] + 2048;
  int*   ri1 = (int*)&es[0][0];
  #pragma unroll
  for (int r = 0; r < 8; ++r) {
    int row = ty * 8 + r;
    rm1[row * 16 + tx] = m1[r]; rm2[row * 16 + tx] = m2[r]; ri1[row * 16 + tx] = i1[r];
  }
  __syncthreads();
  if (t < TMF) {
    float M1 = -FLT_MAX, M2 = -FLT_MAX; int I1 = INT_MAX;
    for (int c = 0; c < 16; ++c) {
      float a1 = rm1[t * 16 + c], a2 = rm2[t * 16 + c]; int ai = ri1[t * 16 + c];
      if (a1 > M1 || (a1 == M1 && ai < I1)) { M2 = fmaxf(M1, a2); M1 = a1; I1 = ai; }
      else M2 = fmaxf(M2, a1);
    }
    size_t gm = (size_t)(mBase + t);
    pm1[gm * NSPLITF + blockIdx.y] = M1;
    pm2[gm * NSPLITF + blockIdx.y] = M2;
    pi1[gm * NSPLITF + blockIdx.y] = I1;
  }
}

// ---------------- K2: merge splits, compute A, flag near-ties ----------------
__global__ void k_merge(const float* __restrict__ z,
                        const float* __restrict__ pm1, const float* __restrict__ pm2,
                        const int* __restrict__ pi1,
                        int* __restrict__ fidx, int* __restrict__ list,
                        int* __restrict__ counter) {
  int m = blockIdx.x * 256 + threadIdx.x;
  float M1 = -FLT_MAX, M2 = -FLT_MAX; int I1 = INT_MAX;
  #pragma unroll
  for (int s = 0; s < NSPLITF; ++s) {
    float a1 = pm1[(size_t)m * NSPLITF + s], a2 = pm2[(size_t)m * NSPLITF + s];
    int   ai = pi1[(size_t)m * NSPLITF + s];
    if (a1 > M1 || (a1 == M1 && ai < I1)) { M2 = fmaxf(M1, a2); M1 = a1; I1 = ai; }
    else M2 = fmaxf(M2, a1);
  }
  double A = 0.0;
  const float4* zr = (const float4*)(z + (size_t)m * DIM);
  for (int q = 0; q < DIM / 4; ++q) {
    float4 v = zr[q];
    A += (double)v.x * v.x + (double)v.y * v.y + (double)v.z * v.z + (double)v.w * v.w;
  }
  float A32 = (float)A;
  // need: unflagged => G-gap > 0.5*ulp(d) + 2*eta.  0.75u (50% headroom) + 2.5e-6 (>=2.5x eta)
  float u   = (A32 > 511.8f) ? 6.1035156e-5f : 3.0517578e-5f;
  float tau = 0.75f * u + 2.5e-6f;
  fidx[m] = I1;
  if (M1 - M2 < tau) { int p = atomicAdd(counter, 1); list[p] = m; }
}

// ---------------- K3: exact npyv rescan, v2: 8 rows x 4 n-splits, 4x4 thread tile ----------------
// grid (NROWS/8, 4), block 256 = rg(2) x cg(128); thread: 4 rows x 4 cols
__global__ __launch_bounds__(256) void k_refine2(
    const float* __restrict__ z, const float* __restrict__ cb,
    const int* __restrict__ list, const int* __restrict__ counter,
    float* __restrict__ rd, int* __restrict__ rn) {
  __shared__ __align__(16) float zs2[8][516];
  __shared__ float est[16][516];
  __shared__ double apart[8][16];
  __shared__ float Arow[8];
  __shared__ int mrow[8];
  __shared__ float rdm[8][128];
  __shared__ int rnm[8][128];

  const int cnt = *counter;
  const int gB = blockIdx.x * 8;
  if (gB >= cnt) return;                    // uniform exit
  const int t = threadIdx.x;
  const int split = blockIdx.y;
  const int nBase0 = split * (NE / 4);      // 2048-entry range
  const int rg = t >> 7, cg = t & 127;

  if (t < 8) mrow[t] = list[(gB + t < cnt) ? gB + t : cnt - 1];
  __syncthreads();
  #pragma unroll
  for (int i = 0; i < 4; ++i) {             // stage 8 z rows
    int li = t + 256 * i; int r = li >> 7, q = li & 127;
    *(float4*)&zs2[r][q * 4] = *(const float4*)(z + (size_t)mrow[r] * DIM + q * 4);
  }
  __syncthreads();
  if (t < 128) {                            // A per row (f64), validated semantics
    int r = t >> 4, seg = t & 15;
    double s = 0.0;
    for (int k = seg * 32; k < seg * 32 + 32; ++k) { double v = zs2[r][k]; s += v * v; }
    apart[r][seg] = s;
  }
  __syncthreads();
  if (t < 8) { double s = 0.0; for (int c2 = 0; c2 < 16; ++c2) s += apart[t][c2]; Arow[t] = (float)s; }
  __syncthreads();

  float bd[4] = {FLT_MAX, FLT_MAX, FLT_MAX, FLT_MAX};
  int   bn[4] = {INT_MAX, INT_MAX, INT_MAX, INT_MAX};

  for (int tile = 0; tile < 4; ++tile) {    // 4 x 512 cols
    const int colBase = nBase0 + tile * 512;
    float L[4][4][4];                       // [row][colj][npyv lane]
    #pragma unroll
    for (int r = 0; r < 4; ++r)
      #pragma unroll
      for (int cj = 0; cj < 4; ++cj)
        #pragma unroll
        for (int j = 0; j < 4; ++j) L[r][cj][j] = 0.0f;

    for (int kc = 0; kc < DIM; kc += 16) {  // 32 chunks of 16 k
      __syncthreads();
      #pragma unroll
      for (int i = 0; i < 8; ++i) {         // stage est[k][col] (k-major, bank-clean)
        int li = t + 256 * i; int col = li >> 2, q = li & 3;
        float4 v = *(const float4*)(cb + (size_t)(colBase + col) * DIM + kc + 4 * q);
        est[4*q+0][col] = v.x; est[4*q+1][col] = v.y;
        est[4*q+2][col] = v.z; est[4*q+3][col] = v.w;
      }
      __syncthreads();
      #pragma unroll
      for (int sub = 3; sub >= 0; --sub) {  // npyv within-chunk order 3,2,1,0
        float zb[4][4], eb[4][4];
        #pragma unroll
        for (int r = 0; r < 4; ++r)
          #pragma unroll
          for (int j = 0; j < 4; ++j)
            zb[r][j] = zs2[rg * 4 + r][kc + 4 * sub + j];   // broadcast
        #pragma unroll
        for (int cj = 0; cj < 4; ++cj)
          #pragma unroll
          for (int j = 0; j < 4; ++j)
            eb[cj][j] = est[4 * sub + j][cg + 128 * cj];    // conflict-free
        #pragma unroll
        for (int r = 0; r < 4; ++r)
          #pragma unroll
          for (int cj = 0; cj < 4; ++cj)
            #pragma unroll
            for (int j = 0; j < 4; ++j)
              L[r][cj][j] = __fadd_rn(L[r][cj][j], __fmul_rn(zb[r][j], eb[cj][j]));
      }
    }
    #pragma unroll
    for (int cj = 0; cj < 4; ++cj)
      #pragma unroll
      for (int r = 0; r < 4; ++r) {
        float G = __fadd_rn(__fadd_rn(L[r][cj][0], L[r][cj][1]),
                            __fadd_rn(L[r][cj][2], L[r][cj][3]));
        float d = __fsub_rn(Arow[rg * 4 + r], __fmul_rn(2.0f, G));
        int n = colBase + cg + 128 * cj;
        if (d < bd[r] || (d == bd[r] && n < bn[r])) { bd[r] = d; bn[r] = n; }
      }
  }
  __syncthreads();
  #pragma unroll
  for (int r = 0; r < 4; ++r) { rdm[rg*4+r][cg] = bd[r]; rnm[rg*4+r][cg] = bn[r]; }
  __syncthreads();
  if (t < 8) {
    float fb = FLT_MAX; int fn = INT_MAX;
    for (int c2 = 0; c2 < 128; ++c2) {
      float d = rdm[t][c2]; int n = rnm[t][c2];
      if (d < fb || (d == fb && n < fn)) { fb = d; fn = n; }
    }
    if (gB + t < cnt) {
      int m = mrow[t];
      rd[(size_t)m * 4 + split] = fb;
      rn[(size_t)m * 4 + split] = fn;
    }
  }
}

// ---------------- K3b: merge refine splits (lex-min d then n) ----------------
__global__ void k_fmerge(const int* __restrict__ list, const int* __restrict__ counter,
                         const float* __restrict__ rd, const int* __restrict__ rn,
                         int* __restrict__ fidx) {
  int i = blockIdx.x * 256 + threadIdx.x;
  if (i >= *counter) return;
  int m = list[i];
  float fb = FLT_MAX; int fn = INT_MAX;
  #pragma unroll
  for (int s = 0; s < 4; ++s) {
    float d = rd[(size_t)m * 4 + s]; int n = rn[(size_t)m * 4 + s];
    if (d < fb || (d == fb && n < fn)) { fb = d; fn = n; }
  }
  fidx[m] = fn;
}

// ---------------- K4: gather z_q + index floats ----------------
__global__ void k_gather(const float* __restrict__ cb, const int* __restrict__ fidx,
                         float* __restrict__ out) {
  __shared__ int idxs[32];
  const int t = threadIdx.x;
  const int mBase = blockIdx.x * 32;
  if (t < 32) {
    int id = fidx[mBase + t];
    idxs[t] = id;
    out[(size_t)NROWS * DIM + mBase + t] = (float)id;
  }
  __syncthreads();
  #pragma unroll
  for (int i = 0; i < 16; ++i) {
    int li = t + i * 256, r = li >> 7, q = li & 127;
    *(float4*)(out + (size_t)(mBase + r) * DIM + q * 4) =
        *(const float4*)(cb + (size_t)idxs[r] * DIM + q * 4);
  }
}

extern "C" void kernel_launch(void* const* d_in, const int* in_sizes, int n_in,
                              void* d_out, int out_size, void* d_ws, size_t ws_size,
                              hipStream_t stream) {
  const float* z  = (const float*)d_in[0];
  const float* cb = (const float*)d_in[1];
  float* out = (float*)d_out;
  char* ws = (char*)d_ws;
  float* pm1 = (float*)(ws + WS_PM1);
  float* pm2 = (float*)(ws + WS_PM2);
  int*   pi1 = (int*)(ws + WS_PI1);
  int*   fidx = (int*)(ws + WS_FIDX);
  int*   list = (int*)(ws + WS_LIST);
  int*   cnt  = (int*)(ws + WS_CNT);

  hipLaunchKernelGGL(k_fast,    dim3(NROWS / TMF, NSPLITF), dim3(256), 0, stream,
                     z, cb, pm1, pm2, pi1, cnt);
  hipLaunchKernelGGL(k_merge,   dim3(NROWS / 256), dim3(256), 0, stream,
                     z, pm1, pm2, pi1, fidx, list, cnt);
  hipLaunchKernelGGL(k_refine2, dim3(NROWS / 8, 4), dim3(256), 0, stream,
                     z, cb, list, cnt, pm1, pi1);
  hipLaunchKernelGGL(k_fmerge,  dim3(NROWS / 256), dim3(256), 0, stream,
                     list, cnt, pm1, pi1, fidx);
  hipLaunchKernelGGL(k_gather,  dim3(NROWS / 32), dim3(256), 0, stream,
                     cb, fidx, out);
}